// Round 3
// baseline (1056.624 us; speedup 1.0000x reference)
//
#include <hip/hip_runtime.h>

#define BB 8
#define CINC 64
#define COUTC 64
#define NN 16384      // H*W
#define HW 128

// ---------------------------------------------------------------------------
// k0: rb[o] = sum_c w_restore[o][c] * b_gat[c]
// ---------------------------------------------------------------------------
__global__ void gat_k0(const float* __restrict__ w_restore,
                       const float* __restrict__ b_gat,
                       float* __restrict__ rb) {
    int t = threadIdx.x;
    if (t < 64) {
        float r = 0.f;
        for (int c = 0; c < 32; ++c) r += w_restore[t * 32 + c] * b_gat[c];
        rb[t] = r;
    }
}

// ---------------------------------------------------------------------------
// k1: reduce conv + head transform + attention logits.
//   red[k]          = sum_cin w_reduce[k][cin] * x[b][cin][v]
//   hmix[b][h*32+c][v] = sum_k w_lin[(h*32+c)][k] * red[k]   (= hfeat)
//   a_s[b][h][v]    = sum_c att_src[h][c] * hmix[h][c][v], a_d likewise
// one thread per node. 512 blocks x 256.
// ---------------------------------------------------------------------------
__global__ __launch_bounds__(256) void gat_k1(
        const float* __restrict__ x, const float* __restrict__ w_reduce,
        const float* __restrict__ w_lin, const float* __restrict__ att_src,
        const float* __restrict__ att_dst, float* __restrict__ hmix,
        float* __restrict__ as_ws, float* __restrict__ ad_ws) {
    __shared__ float wred[32 * 64];
    __shared__ float wlin[128 * 32];
    __shared__ float asrc[128];
    __shared__ float adst[128];
    int tid = threadIdx.x;
    for (int t = tid; t < 2048; t += 256) wred[t] = w_reduce[t];
    for (int t = tid; t < 4096; t += 256) wlin[t] = w_lin[t];
    if (tid < 128) { asrc[tid] = att_src[tid]; adst[tid] = att_dst[tid]; }
    __syncthreads();

    int gid = blockIdx.x * 256 + tid;
    int b = gid >> 14;
    int v = gid & (NN - 1);

    const float* xb = x + ((size_t)b * CINC) * NN + v;
    float xv[64];
#pragma unroll
    for (int c = 0; c < 64; ++c) xv[c] = xb[(size_t)c * NN];

    float red[32];
#pragma unroll
    for (int k = 0; k < 32; ++k) {
        const float4* w4 = reinterpret_cast<const float4*>(&wred[k * 64]);
        float acc = 0.f;
#pragma unroll
        for (int c4 = 0; c4 < 16; ++c4) {
            float4 w = w4[c4];
            acc += w.x * xv[4 * c4] + w.y * xv[4 * c4 + 1] +
                   w.z * xv[4 * c4 + 2] + w.w * xv[4 * c4 + 3];
        }
        red[k] = acc;
    }

    float* hb = hmix + ((size_t)b * 128) * NN + v;
#pragma unroll
    for (int h = 0; h < 4; ++h) {
        float hm[32];
#pragma unroll
        for (int c = 0; c < 32; ++c) {
            const float4* w4 =
                reinterpret_cast<const float4*>(&wlin[(h * 32 + c) * 32]);
            float acc = 0.f;
#pragma unroll
            for (int k4 = 0; k4 < 8; ++k4) {
                float4 w = w4[k4];
                acc += w.x * red[4 * k4] + w.y * red[4 * k4 + 1] +
                       w.z * red[4 * k4 + 2] + w.w * red[4 * k4 + 3];
            }
            hm[c] = acc;
        }
        float as = 0.f, ad = 0.f;
#pragma unroll
        for (int c = 0; c < 32; ++c) {
            as += asrc[h * 32 + c] * hm[c];
            ad += adst[h * 32 + c] * hm[c];
        }
#pragma unroll
        for (int c = 0; c < 32; ++c)
            hb[(size_t)(h * 32 + c) * NN] = hm[c];
        as_ws[((size_t)b * 4 + h) * NN + v] = as;
        ad_ws[((size_t)b * 4 + h) * NN + v] = ad;
    }
}

// ---------------------------------------------------------------------------
// k2: stencil softmax + aggregation over PRE-TRANSFORMED features (hmix) +
//     restore conv + residual + BN partial sums.
// Per-thread state: g[32] + alpha[5][4] only (round-2's racc arrays spilled).
// 512 blocks x 256.
// ---------------------------------------------------------------------------
__global__ __launch_bounds__(256) void gat_k2(
        const float* __restrict__ x, const float* __restrict__ w_restore,
        const float* __restrict__ rb, const float* __restrict__ hmix,
        const float* __restrict__ as_ws, const float* __restrict__ ad_ws,
        float* __restrict__ outp, float* __restrict__ stats) {
    __shared__ float wres_lds[64 * 32];
    __shared__ float rb_lds[64];
    __shared__ float g_tile[32][256];

    int tid = threadIdx.x;
    for (int t = tid; t < 2048; t += 256) wres_lds[t] = w_restore[t];
    if (tid < 64) rb_lds[tid] = rb[tid];
    __syncthreads();

    int base = blockIdx.x * 256;
    int b = base >> 14;
    int v0 = base & (NN - 1);
    int v = v0 + tid;
    int i = v >> 7, j = v & 127;

    // ---- attention weights ----
    float adv[4];
    const float* adp = ad_ws + (size_t)b * 4 * NN + v;
#pragma unroll
    for (int h = 0; h < 4; ++h) adv[h] = adp[(size_t)h * NN];

    bool nu = i > 0, ndn = i < 127, nl = j > 0, nr = j < 127;
    int un[5] = { v, nu ? v - 128 : v, ndn ? v + 128 : v,
                  nl ? v - 1 : v, nr ? v + 1 : v };
    float msk[5] = { 0.f, nu ? 0.f : -1e30f, ndn ? 0.f : -1e30f,
                     nl ? 0.f : -1e30f, nr ? 0.f : -1e30f };

    float al[5][4];
    const float* asp = as_ws + (size_t)b * 4 * NN;
#pragma unroll
    for (int n = 0; n < 5; ++n) {
#pragma unroll
        for (int h = 0; h < 4; ++h) {
            float e = asp[(size_t)h * NN + un[n]] + adv[h];
            e = e > 0.f ? e : 0.2f * e;          // leaky_relu(0.2)
            al[n][h] = e + msk[n];
        }
    }
#pragma unroll
    for (int h = 0; h < 4; ++h) {
        float m = al[0][h];
#pragma unroll
        for (int n = 1; n < 5; ++n) m = fmaxf(m, al[n][h]);
        float den = 0.f;
#pragma unroll
        for (int n = 0; n < 5; ++n) {
            float ex = __expf(al[n][h] - m);
            al[n][h] = ex; den += ex;
        }
        float inv = 0.25f / den;                 // fold head-mean /4 here
#pragma unroll
        for (int n = 0; n < 5; ++n) al[n][h] *= inv;
    }

    // ---- weighted 5-tap stencil over hmix, accumulate g[32] ----
    float g[32];
#pragma unroll
    for (int c = 0; c < 32; ++c) g[c] = 0.f;

    const float* hb = hmix + (size_t)b * 128 * NN;
#pragma unroll
    for (int n = 0; n < 5; ++n) {
        const float* hn = hb + un[n];
#pragma unroll
        for (int h = 0; h < 4; ++h) {
            float a = al[n][h];
            const float* hh = hn + (size_t)(h * 32) * NN;
#pragma unroll
            for (int c = 0; c < 32; ++c)
                g[c] = fmaf(a, hh[(size_t)c * NN], g[c]);
        }
    }
#pragma unroll
    for (int c = 0; c < 32; ++c) g_tile[c][tid] = g[c];
    __syncthreads();

    // ---- restore conv + residual + BN partial sums ----
    int wv = tid >> 6, lane = tid & 63;
    float s1[16], s2[16];
#pragma unroll
    for (int o = 0; o < 16; ++o) { s1[o] = 0.f; s2[o] = 0.f; }

    const float* xb = x + (size_t)b * CINC * NN;
    float* ob = outp + (size_t)b * COUTC * NN;
#pragma unroll
    for (int grp = 0; grp < 4; ++grp) {
        int nd = grp * 64 + lane;
        int vg = v0 + nd;
        float gv[32];
#pragma unroll
        for (int c = 0; c < 32; ++c) gv[c] = g_tile[c][nd];
#pragma unroll
        for (int o = 0; o < 16; ++o) {
            int och = wv * 16 + o;
            float acc = rb_lds[och];
            const float4* w4 =
                reinterpret_cast<const float4*>(&wres_lds[och * 32]);
#pragma unroll
            for (int c4 = 0; c4 < 8; ++c4) {
                float4 w = w4[c4];
                acc += w.x * gv[4 * c4] + w.y * gv[4 * c4 + 1] +
                       w.z * gv[4 * c4 + 2] + w.w * gv[4 * c4 + 3];
            }
            acc += xb[(size_t)och * NN + vg];      // residual
            ob[(size_t)och * NN + vg] = acc;
            s1[o] += acc; s2[o] += acc * acc;
        }
    }

#pragma unroll
    for (int o = 0; o < 16; ++o) {
        float r1 = s1[o], r2 = s2[o];
        for (int off = 32; off > 0; off >>= 1) {
            r1 += __shfl_xor(r1, off, 64);
            r2 += __shfl_xor(r2, off, 64);
        }
        if (lane == 0) {
            int och = wv * 16 + o;
            atomicAdd(&stats[och], r1);
            atomicAdd(&stats[64 + och], r2);
        }
    }
}

// ---------------------------------------------------------------------------
// k3: BN (batch stats) + ReLU, in place on d_out. float4 per thread.
// ---------------------------------------------------------------------------
__global__ __launch_bounds__(256) void gat_k3(
        float* __restrict__ out, const float* __restrict__ stats,
        const float* __restrict__ gamma, const float* __restrict__ beta) {
    int f = blockIdx.x * 256 + threadIdx.x;
    int e = f * 4;
    int c = (e >> 14) & 63;
    const float cnt_inv = 1.f / 131072.f;   // B*H*W
    float mean = stats[c] * cnt_inv;
    float var = stats[64 + c] * cnt_inv - mean * mean;
    float inv = rsqrtf(var + 1e-5f);
    float sc = gamma[c] * inv;
    float sh = beta[c] - mean * sc;
    float4 vv = reinterpret_cast<float4*>(out)[f];
    vv.x = fmaxf(vv.x * sc + sh, 0.f);
    vv.y = fmaxf(vv.y * sc + sh, 0.f);
    vv.z = fmaxf(vv.z * sc + sh, 0.f);
    vv.w = fmaxf(vv.w * sc + sh, 0.f);
    reinterpret_cast<float4*>(out)[f] = vv;
}

// ---------------------------------------------------------------------------
extern "C" void kernel_launch(void* const* d_in, const int* in_sizes, int n_in,
                              void* d_out, int out_size, void* d_ws, size_t ws_size,
                              hipStream_t stream) {
    const float* x         = (const float*)d_in[0];
    const float* w_reduce  = (const float*)d_in[1];
    const float* w_lin     = (const float*)d_in[2];
    const float* att_src   = (const float*)d_in[3];
    const float* att_dst   = (const float*)d_in[4];
    const float* b_gat     = (const float*)d_in[5];
    const float* w_restore = (const float*)d_in[6];
    const float* bn_gamma  = (const float*)d_in[7];
    const float* bn_beta   = (const float*)d_in[8];
    // src/dst (d_in[9], d_in[10]) unused: the grid structure is known.

    float* ws     = (float*)d_ws;
    float* hmix   = ws;                       // 8*128*16384 = 16,777,216
    float* as_ws  = hmix + 16777216;          // 8*4*16384   =    524,288
    float* ad_ws  = as_ws + 524288;           //                  524,288
    float* rbf    = ad_ws + 524288;           // 64
    float* stats  = rbf + 64;                 // 128 (sum[64], sumsq[64])

    hipMemsetAsync(stats, 0, 128 * sizeof(float), stream);

    gat_k0<<<1, 64, 0, stream>>>(w_restore, b_gat, rbf);
    gat_k1<<<512, 256, 0, stream>>>(x, w_reduce, w_lin, att_src, att_dst,
                                    hmix, as_ws, ad_ws);
    gat_k2<<<512, 256, 0, stream>>>(x, w_restore, rbf, hmix, as_ws, ad_ws,
                                    (float*)d_out, stats);
    gat_k3<<<8192, 256, 0, stream>>>((float*)d_out, stats, bn_gamma, bn_beta);
}

// Round 4
// 354.893 us; speedup vs baseline: 2.9773x; 2.9773x over previous
//
#include <hip/hip_runtime.h>

#define NN 16384      // H*W, 128x128
#define CINC 64

// ---------------------------------------------------------------------------
// k0: rb[o] = sum_c w_restore[o][c] * b_gat[c]
// ---------------------------------------------------------------------------
__global__ void gat_k0(const float* __restrict__ w_restore,
                       const float* __restrict__ b_gat,
                       float* __restrict__ rb) {
    int t = threadIdx.x;
    if (t < 64) {
        float r = 0.f;
        for (int c = 0; c < 32; ++c) r += w_restore[t * 32 + c] * b_gat[c];
        rb[t] = r;
    }
}

// ---------------------------------------------------------------------------
// k1: reduce conv + head transform + attention logits.
// Channel-split mapping: t = grp*32 + nd_lo (8 groups x 32 nodes),
// 8 sub-iterations -> 256 nodes per block. No thread ever owns a big
// accumulator array next to strided global loads (rounds 1-3 all spilled).
// ---------------------------------------------------------------------------
__global__ __launch_bounds__(256) void gat_k1(
        const float* __restrict__ x, const float* __restrict__ w_reduce,
        const float* __restrict__ w_lin, const float* __restrict__ att_src,
        const float* __restrict__ att_dst, float* __restrict__ hmix,
        float* __restrict__ as_ws, float* __restrict__ ad_ws) {
    __shared__ float wred_lds[2048];     // [32][64]
    __shared__ float wlin_lds[4096];     // [128][32]
    __shared__ float asrc[128];
    __shared__ float adst[128];
    __shared__ float red_lds[256][33];   // pad 33: conflict-free lane-varying rows

    int tid = threadIdx.x;
    for (int t = tid; t < 2048; t += 256) wred_lds[t] = w_reduce[t];
    for (int t = tid; t < 4096; t += 256) wlin_lds[t] = w_lin[t];
    if (tid < 128) { asrc[tid] = att_src[tid]; adst[tid] = att_dst[tid]; }
    __syncthreads();

    int base = blockIdx.x << 8;
    int b = base >> 14;
    int v0 = base & (NN - 1);
    int nd_lo = tid & 31, grp = tid >> 5;

    // ---- phase A: reduced features, 4 k-channels per group ----
    {
        int k0 = grp * 4;
        const float* xb = x + (size_t)b * CINC * NN;
#pragma unroll 1
        for (int sub = 0; sub < 8; ++sub) {
            int nd = sub * 32 + nd_lo;
            const float* xp = xb + v0 + nd;
            float a0 = 0.f, a1 = 0.f, a2 = 0.f, a3 = 0.f;
#pragma unroll 8
            for (int c = 0; c < 64; ++c) {
                float xc = xp[(size_t)c * NN];
                a0 = fmaf(wred_lds[(k0 + 0) * 64 + c], xc, a0);
                a1 = fmaf(wred_lds[(k0 + 1) * 64 + c], xc, a1);
                a2 = fmaf(wred_lds[(k0 + 2) * 64 + c], xc, a2);
                a3 = fmaf(wred_lds[(k0 + 3) * 64 + c], xc, a3);
            }
            red_lds[nd][k0 + 0] = a0;
            red_lds[nd][k0 + 1] = a1;
            red_lds[nd][k0 + 2] = a2;
            red_lds[nd][k0 + 3] = a3;
        }
    }
    __syncthreads();

    // ---- phase B: head transform (16 hm-channels per group) + logits ----
    {
        int h = grp >> 1, lc0 = (grp & 1) * 16;
        float* hb = hmix + (size_t)b * 128 * NN + v0;
#pragma unroll 1
        for (int sub = 0; sub < 8; ++sub) {
            int nd = sub * 32 + nd_lo;
            float rv[32];
#pragma unroll
            for (int k = 0; k < 32; ++k) rv[k] = red_lds[nd][k];

            float pas = 0.f, pad_ = 0.f;
#pragma unroll
            for (int oo = 0; oo < 16; ++oo) {
                int ch = h * 32 + lc0 + oo;
                const float* wl = &wlin_lds[ch * 32];
                float acc = 0.f;
#pragma unroll
                for (int k = 0; k < 32; ++k) acc = fmaf(wl[k], rv[k], acc);
                hb[(size_t)ch * NN + nd] = acc;
                pas = fmaf(asrc[ch], acc, pas);
                pad_ = fmaf(adst[ch], acc, pad_);
            }
            pas += __shfl_xor(pas, 32, 64);
            pad_ += __shfl_xor(pad_, 32, 64);
            if ((grp & 1) == 0) {
                as_ws[((size_t)b * 4 + h) * NN + v0 + nd] = pas;
                ad_ws[((size_t)b * 4 + h) * NN + v0 + nd] = pad_;
            }
        }
    }
}

// ---------------------------------------------------------------------------
// k2: stencil softmax (per-node) + aggregation (4 out-ch per group) +
//     restore conv (8 out-ch per group) + residual + BN partial sums.
// ---------------------------------------------------------------------------
__global__ __launch_bounds__(256) void gat_k2(
        const float* __restrict__ x, const float* __restrict__ w_restore,
        const float* __restrict__ rb, const float* __restrict__ hmix,
        const float* __restrict__ as_ws, const float* __restrict__ ad_ws,
        float* __restrict__ outp, float* __restrict__ stats) {
    __shared__ float wres_lds[2048];     // [64][32]
    __shared__ float rb_lds[64];
    __shared__ float al_lds[256][21];    // 20 alphas, pad 21 (coprime 32)
    __shared__ float g_lds[256][33];     // 32 g-channels, pad 33

    int tid = threadIdx.x;
    for (int t = tid; t < 2048; t += 256) wres_lds[t] = w_restore[t];
    if (tid < 64) rb_lds[tid] = rb[tid];

    int base = blockIdx.x << 8;
    int b = base >> 14;
    int v0 = base & (NN - 1);

    // ---- phase 1: softmax alphas, one node per thread ----
    {
        int v = v0 + tid;
        int i = v >> 7, j = v & 127;
        float adv[4];
        const float* adp = ad_ws + (size_t)b * 4 * NN + v;
#pragma unroll
        for (int h = 0; h < 4; ++h) adv[h] = adp[(size_t)h * NN];

        bool nu = i > 0, ndn = i < 127, nl = j > 0, nr = j < 127;
        int un[5] = { v, nu ? v - 128 : v, ndn ? v + 128 : v,
                      nl ? v - 1 : v, nr ? v + 1 : v };
        float msk[5] = { 0.f, nu ? 0.f : -1e30f, ndn ? 0.f : -1e30f,
                         nl ? 0.f : -1e30f, nr ? 0.f : -1e30f };

        float al[5][4];
        const float* asp = as_ws + (size_t)b * 4 * NN;
#pragma unroll
        for (int n = 0; n < 5; ++n)
#pragma unroll
            for (int h = 0; h < 4; ++h) {
                float e = asp[(size_t)h * NN + un[n]] + adv[h];
                e = e > 0.f ? e : 0.2f * e;      // leaky_relu(0.2)
                al[n][h] = e + msk[n];
            }
#pragma unroll
        for (int h = 0; h < 4; ++h) {
            float m = al[0][h];
#pragma unroll
            for (int n = 1; n < 5; ++n) m = fmaxf(m, al[n][h]);
            float den = 0.f;
#pragma unroll
            for (int n = 0; n < 5; ++n) {
                float ex = __expf(al[n][h] - m);
                al[n][h] = ex; den += ex;
            }
            float inv = 0.25f / den;             // fold head-mean
#pragma unroll
            for (int n = 0; n < 5; ++n) al_lds[tid][n * 4 + h] = al[n][h] * inv;
        }
    }
    __syncthreads();

    int nd_lo = tid & 31, grp = tid >> 5;

    // ---- phase 2: weighted 5-tap stencil, 4 output channels per group ----
    {
        int c0 = grp * 4;
        const float* hb = hmix + (size_t)b * 128 * NN;
#pragma unroll 1
        for (int sub = 0; sub < 8; ++sub) {
            int nd = sub * 32 + nd_lo;
            int v = v0 + nd;
            int i = v >> 7, j = v & 127;
            int un[5] = { v, i > 0 ? v - 128 : v, i < 127 ? v + 128 : v,
                          j > 0 ? v - 1 : v, j < 127 ? v + 1 : v };
            float a[20];
#pragma unroll
            for (int q = 0; q < 20; ++q) a[q] = al_lds[nd][q];

            float g0 = 0.f, g1 = 0.f, g2 = 0.f, g3 = 0.f;
#pragma unroll
            for (int n = 0; n < 5; ++n) {
                const float* hn = hb + un[n] + (size_t)c0 * NN;
#pragma unroll
                for (int h = 0; h < 4; ++h) {
                    float av = a[n * 4 + h];
                    const float* hp = hn + (size_t)(h * 32) * NN;
                    g0 = fmaf(av, hp[0], g0);
                    g1 = fmaf(av, hp[NN], g1);
                    g2 = fmaf(av, hp[2 * NN], g2);
                    g3 = fmaf(av, hp[3 * NN], g3);
                }
            }
            g_lds[nd][c0 + 0] = g0;
            g_lds[nd][c0 + 1] = g1;
            g_lds[nd][c0 + 2] = g2;
            g_lds[nd][c0 + 3] = g3;
        }
    }
    __syncthreads();

    // ---- phase 3: restore conv + residual + BN sums, 8 out-ch per group ----
    {
        int o0 = grp * 8;
        const float* xb = x + (size_t)b * CINC * NN;
        float* ob = outp + (size_t)b * CINC * NN;
        float s1[8], s2[8];
#pragma unroll
        for (int o = 0; o < 8; ++o) { s1[o] = 0.f; s2[o] = 0.f; }

#pragma unroll 1
        for (int sub = 0; sub < 8; ++sub) {
            int nd = sub * 32 + nd_lo;
            int vg = v0 + nd;
            float acc[8];
#pragma unroll
            for (int o = 0; o < 8; ++o) acc[o] = rb_lds[o0 + o];
#pragma unroll
            for (int c = 0; c < 32; ++c) {
                float gv = g_lds[nd][c];
#pragma unroll
                for (int o = 0; o < 8; ++o)
                    acc[o] = fmaf(wres_lds[(o0 + o) * 32 + c], gv, acc[o]);
            }
#pragma unroll
            for (int o = 0; o < 8; ++o) {
                float r = acc[o] + xb[(size_t)(o0 + o) * NN + vg];
                ob[(size_t)(o0 + o) * NN + vg] = r;
                s1[o] += r; s2[o] += r * r;
            }
        }
#pragma unroll
        for (int o = 0; o < 8; ++o) {
            float r1 = s1[o], r2 = s2[o];
            for (int off = 16; off > 0; off >>= 1) {
                r1 += __shfl_xor(r1, off, 64);
                r2 += __shfl_xor(r2, off, 64);
            }
            if (nd_lo == 0) {
                atomicAdd(&stats[o0 + o], r1);
                atomicAdd(&stats[64 + o0 + o], r2);
            }
        }
    }
}

// ---------------------------------------------------------------------------
// k3: BN (batch stats) + ReLU, in place on d_out. float4 per thread.
// ---------------------------------------------------------------------------
__global__ __launch_bounds__(256) void gat_k3(
        float* __restrict__ out, const float* __restrict__ stats,
        const float* __restrict__ gamma, const float* __restrict__ beta) {
    int f = blockIdx.x * 256 + threadIdx.x;
    int e = f * 4;
    int c = (e >> 14) & 63;
    const float cnt_inv = 1.f / 131072.f;   // B*H*W
    float mean = stats[c] * cnt_inv;
    float var = stats[64 + c] * cnt_inv - mean * mean;
    float inv = rsqrtf(var + 1e-5f);
    float sc = gamma[c] * inv;
    float sh = beta[c] - mean * sc;
    float4 vv = reinterpret_cast<float4*>(out)[f];
    vv.x = fmaxf(vv.x * sc + sh, 0.f);
    vv.y = fmaxf(vv.y * sc + sh, 0.f);
    vv.z = fmaxf(vv.z * sc + sh, 0.f);
    vv.w = fmaxf(vv.w * sc + sh, 0.f);
    reinterpret_cast<float4*>(out)[f] = vv;
}

// ---------------------------------------------------------------------------
extern "C" void kernel_launch(void* const* d_in, const int* in_sizes, int n_in,
                              void* d_out, int out_size, void* d_ws, size_t ws_size,
                              hipStream_t stream) {
    const float* x         = (const float*)d_in[0];
    const float* w_reduce  = (const float*)d_in[1];
    const float* w_lin     = (const float*)d_in[2];
    const float* att_src   = (const float*)d_in[3];
    const float* att_dst   = (const float*)d_in[4];
    const float* b_gat     = (const float*)d_in[5];
    const float* w_restore = (const float*)d_in[6];
    const float* bn_gamma  = (const float*)d_in[7];
    const float* bn_beta   = (const float*)d_in[8];
    // src/dst (d_in[9], d_in[10]) unused: the grid structure is known.

    float* ws     = (float*)d_ws;
    float* hmix   = ws;                       // 8*128*16384 = 16,777,216
    float* as_ws  = hmix + 16777216;          // 8*4*16384   =    524,288
    float* ad_ws  = as_ws + 524288;           //                  524,288
    float* rbf    = ad_ws + 524288;           // 64
    float* stats  = rbf + 64;                 // 128 (sum[64], sumsq[64])

    hipMemsetAsync(stats, 0, 128 * sizeof(float), stream);

    gat_k0<<<1, 64, 0, stream>>>(w_restore, b_gat, rbf);
    gat_k1<<<512, 256, 0, stream>>>(x, w_reduce, w_lin, att_src, att_dst,
                                    hmix, as_ws, ad_ws);
    gat_k2<<<512, 256, 0, stream>>>(x, w_restore, rbf, hmix, as_ws, ad_ws,
                                    (float*)d_out, stats);
    gat_k3<<<8192, 256, 0, stream>>>((float*)d_out, stats, bn_gamma, bn_beta);
}